// Round 15
// baseline (314.258 us; speedup 1.0000x reference)
//
#include <hip/hip_runtime.h>
#include <hip/hip_bf16.h>

// FraudSNN fused kernel: GEMM (bf16 MFMA) + LIF recurrence, T=10, F=256, H=512.
// R15: (a) back to the PROVEN 0-conflict xt layout ([132]-stride halves; R14's [264]
// full-row cost 10.5M bank-conflict cycles); (b) 2-t fusion: GEMM(t)+GEMM(t+1) per
// barrier pair (only LIF is sequential), acc[2t][2rt][2c]=32 regs per ct-pair pass,
// LIF(t)/LIF(t+1) back-to-back per mem1 plane (1 LDS RMW for 2 updates), red[2],
// 1 barrier/t, W1 L2 reads halved. All 8 mem1 planes in LDS (occupancy is 1 blk/CU
// in every measured round -> spend LDS, save regs). LDS 101.6 KB; live ~105 < 128.

typedef short short8 __attribute__((ext_vector_type(8)));
typedef float f32x4 __attribute__((ext_vector_type(4)));

__device__ __forceinline__ unsigned short bfbits(float f) {
  union { __hip_bfloat16 h; unsigned short u; } c;
  c.h = __float2bfloat16(f);   // hardware RNE
  return c.u;
}

__device__ __forceinline__ unsigned int bfpack(float a, float b) {
  return (unsigned int)bfbits(a) | ((unsigned int)bfbits(b) << 16);
}

__device__ __forceinline__ float fast_sigmoid(float z) {
  float e = __expf(-z);
  return __builtin_amdgcn_rcpf(1.0f + e);
}

__device__ __forceinline__ void lif4(f32x4& mv, const f32x4 av, float w2c, float pr[4]) {
#pragma unroll
  for (int e = 0; e < 4; ++e) {
    float m   = fmaf(mv[e], 0.9f, av[e]);     // beta*mem + cur1
    float spk = fast_sigmoid(fmaf(m, 10.f, -10.f));
    mv[e] = m - spk;
    pr[e] = fmaf(spk, w2c, pr[e]);
  }
}

__global__ void w1_to_bf16(const float* __restrict__ w1, unsigned short* __restrict__ o) {
  int i = blockIdx.x * 256 + threadIdx.x;      // 32768 float4s
  float4 v = reinterpret_cast<const float4*>(w1)[i];
  reinterpret_cast<uint2*>(o)[i] = make_uint2(bfpack(v.x, v.y), bfpack(v.z, v.w));
}

__device__ __forceinline__ short8 cvt_frag(const float* p) {
  const float4 v0 = *reinterpret_cast<const float4*>(p);
  const float4 v1 = *reinterpret_cast<const float4*>(p + 4);
  union { unsigned int u[4]; short8 s; } cv;
  cv.u[0] = bfpack(v0.x, v0.y);
  cv.u[1] = bfpack(v0.z, v0.w);
  cv.u[2] = bfpack(v1.x, v1.y);
  cv.u[3] = bfpack(v1.z, v1.w);
  return cv.s;
}

// 512 threads = 8 waves. Block: 32 batch rows; wave w owns 32 rows x h in [w*64, w*64+64).
template <bool USE_WS>
__global__
__attribute__((amdgpu_flat_work_group_size(512, 512)))
void snn_main(const float* __restrict__ x,
              const unsigned short* __restrict__ w1bf,  // bf16 W1 (if USE_WS)
              const float* __restrict__ w1f,            // fp32 W1 (fallback)
              const float* __restrict__ b1,
              const float* __restrict__ w2,
              const float* __restrict__ b2,
              float* __restrict__ out)
{
  __shared__ __align__(16) float mem_lds[8][512][4];          // 65,536 B (0-conflict slots)
  __shared__ __align__(16) unsigned short xt[2][2][32][132];  // [t][half][row][col] 33,792 B
  __shared__ float red[2][32][9];                             // [t][row][wave] 2,304 B

  const int tid  = threadIdx.x;
  const int lane = tid & 63;
  const int wave = tid >> 6;          // 0..7
  const int l15  = lane & 15;
  const int lq   = lane >> 4;         // 0..3
  const long b0  = (long)blockIdx.x * 32;
  const int h0   = wave * 64;         // 4 col-tiles of 16

  float w2l[4], b1l[4];
#pragma unroll
  for (int ct = 0; ct < 4; ++ct) {
    int h = h0 + ct * 16 + l15;
    w2l[ct] = w2[h];
    b1l[ct] = b1[h];
  }
  const float bias2 = b2[0];

#pragma unroll
  for (int p = 0; p < 8; ++p) {
    f32x4 z = {0.f, 0.f, 0.f, 0.f};
    *reinterpret_cast<f32x4*>(&mem_lds[p][tid][0]) = z;
  }

  float mem2 = 0.f, spksum = 0.f;   // per-thread redundant (16 replicas per row)

  // staging: thread -> row sr (0..31), float4 col sc (0..15); 4 float4 per t
  const int sr = tid >> 4;
  const int sc = tid & 15;
  const float* xrow = x + (b0 + sr) * 2560;

  const unsigned short* wb = w1bf + (h0 + l15) * 256 + lq * 8;
  const float*          wf = w1f  + (h0 + l15) * 256 + lq * 8;

  // prologue: load+pack t=0,1 (pf = 8 uint2 = 16 VGPR)
  uint2 pf[8];
#pragma unroll
  for (int tl = 0; tl < 2; ++tl)
#pragma unroll
    for (int j = 0; j < 4; ++j) {
      const float4 v = *reinterpret_cast<const float4*>(xrow + tl * 256 + sc * 4 + j * 64);
      pf[tl * 4 + j] = make_uint2(bfpack(v.x, v.y), bfpack(v.z, v.w));
    }

#pragma unroll 1
  for (int tt = 0; tt < 10; tt += 2) {
    // ---- A: write pf -> xt (both t, both halves); issue loads for tt+2, tt+3 ----
#pragma unroll
    for (int tl = 0; tl < 2; ++tl)
#pragma unroll
      for (int j = 0; j < 4; ++j)
        *reinterpret_cast<uint2*>(&xt[tl][j >> 1][sr][sc * 4 + (j & 1) * 64]) = pf[tl * 4 + j];
    {
      const int t2 = (tt < 8) ? tt + 2 : 8;   // tail: harmless re-read of t=8,9
#pragma unroll
      for (int tl = 0; tl < 2; ++tl)
#pragma unroll
        for (int j = 0; j < 4; ++j) {
          const float4 v = *reinterpret_cast<const float4*>(
              xrow + (t2 + tl) * 256 + sc * 4 + j * 64);
          pf[tl * 4 + j] = make_uint2(bfpack(v.x, v.y), bfpack(v.z, v.w));
        }
    }
    __syncthreads();   // bar1: xt ready for both t

    // ======== two ct-pair passes; acc[t][rt][c] = 32 regs per pass ========
#pragma unroll 1
    for (int cp = 0; cp < 2; ++cp) {
      const int cbase = cp * 2;
      f32x4 acc[2][2][2];
#pragma unroll
      for (int tl = 0; tl < 2; ++tl)
#pragma unroll
        for (int rt = 0; rt < 2; ++rt)
#pragma unroll
          for (int c = 0; c < 2; ++c) {
            f32x4 cc = { b1l[cbase + c], b1l[cbase + c], b1l[cbase + c], b1l[cbase + c] };
            acc[tl][rt][c] = cc;
          }

#pragma unroll
      for (int kk = 0; kk < 8; ++kk) {
        short8 a[2][2], bfr[2];
#pragma unroll
        for (int tl = 0; tl < 2; ++tl)
#pragma unroll
          for (int rt = 0; rt < 2; ++rt)
            a[tl][rt] = *reinterpret_cast<const short8*>(
                &xt[tl][kk >> 2][rt * 16 + l15][(kk & 3) * 32 + lq * 8]);
#pragma unroll
        for (int c = 0; c < 2; ++c) {
          if constexpr (USE_WS)
            bfr[c] = *reinterpret_cast<const short8*>(wb + (cbase + c) * 4096 + kk * 32);
          else
            bfr[c] = cvt_frag(wf + (cbase + c) * 4096 + kk * 32);
        }
#pragma unroll
        for (int tl = 0; tl < 2; ++tl)
#pragma unroll
          for (int rt = 0; rt < 2; ++rt)
#pragma unroll
            for (int c = 0; c < 2; ++c)
              acc[tl][rt][c] = __builtin_amdgcn_mfma_f32_16x16x32_bf16(
                  a[tl][rt], bfr[c], acc[tl][rt][c], 0, 0, 0);
      }

      // LIF for this ct-pair: per (rt), per c: one plane RMW covers both t updates
#pragma unroll
      for (int rt = 0; rt < 2; ++rt) {
        float pr0[4] = {0.f, 0.f, 0.f, 0.f};
        float pr1[4] = {0.f, 0.f, 0.f, 0.f};
#pragma unroll
        for (int c = 0; c < 2; ++c) {
          const int p = rt * 4 + cbase + c;
          f32x4* slot = reinterpret_cast<f32x4*>(&mem_lds[p][tid][0]);
          f32x4 mv = *slot;
          lif4(mv, acc[0][rt][c], w2l[cbase + c], pr0);   // t
          lif4(mv, acc[1][rt][c], w2l[cbase + c], pr1);   // t+1
          *slot = mv;
        }
#pragma unroll
        for (int e = 0; e < 4; ++e) {
          float v0 = pr0[e];
          v0 += __shfl_xor(v0, 1); v0 += __shfl_xor(v0, 2);
          v0 += __shfl_xor(v0, 4); v0 += __shfl_xor(v0, 8);
          float v1 = pr1[e];
          v1 += __shfl_xor(v1, 1); v1 += __shfl_xor(v1, 2);
          v1 += __shfl_xor(v1, 4); v1 += __shfl_xor(v1, 8);
          if (l15 == 0) {
            if (cp == 0) {
              red[0][rt * 16 + lq * 4 + e][wave] = v0;
              red[1][rt * 16 + lq * 4 + e][wave] = v1;
            } else {
              red[0][rt * 16 + lq * 4 + e][wave] += v0;
              red[1][rt * 16 + lq * 4 + e][wave] += v1;
            }
          }
        }
      }
    }
    __syncthreads();   // bar2: red complete for both t; xt reads done

    // ---- LIF2 twice (redundant on all threads, row = lane&31) ----
#pragma unroll
    for (int tl = 0; tl < 2; ++tl) {
      float c2 = bias2;
#pragma unroll
      for (int w = 0; w < 8; ++w) c2 += red[tl][lane & 31][w];
      float m   = fmaf(mem2, 0.9f, c2);
      float spk = fast_sigmoid(fmaf(m, 10.f, -10.f));
      mem2   = m - spk;
      spksum += spk;
    }
  }

  if (tid < 32) {
    float y = fast_sigmoid(spksum * 0.1f);
    out[b0 + tid] = y;                      // FLOAT32 output
  }
}

extern "C" void kernel_launch(void* const* d_in, const int* in_sizes, int n_in,
                              void* d_out, int out_size, void* d_ws, size_t ws_size,
                              hipStream_t stream) {
  const float* x  = (const float*)d_in[0];
  const float* W1 = (const float*)d_in[1];
  const float* b1 = (const float*)d_in[2];
  const float* W2 = (const float*)d_in[3];
  const float* b2 = (const float*)d_in[4];
  float* out = (float*)d_out;
  (void)in_sizes; (void)n_in;

  const int grid = out_size / 32;   // out_size == B == 32768 -> 1024 blocks

  if (ws_size >= 512 * 256 * sizeof(unsigned short)) {
    unsigned short* w1bf = (unsigned short*)d_ws;   // 256 KB
    w1_to_bf16<<<128, 256, 0, stream>>>(W1, w1bf);
    snn_main<true><<<grid, 512, 0, stream>>>(x, w1bf, W1, b1, W2, b2, out);
  } else {
    snn_main<false><<<grid, 512, 0, stream>>>(x, nullptr, W1, b1, W2, b2, out);
  }
}

// Round 16
// 226.465 us; speedup vs baseline: 1.3877x; 1.3877x over previous
//
#include <hip/hip_runtime.h>
#include <hip/hip_bf16.h>

// FraudSNN fused kernel: GEMM (bf16 MFMA) + LIF recurrence, T=10, F=256, H=512.
// R16: R14 (222us, spill-free, 2 barriers/t, full-phase prefetch cover) with its ONE
// defect fixed: xt[32][264] (stride 132 dw = 4 mod 32 -> 8-way bank conflict, 10.5M
// conflict cycles) -> xt[2][32][132] halves (stride 66 dw = 2 mod 32, measured
// 0-conflict in R7-R13). Both halves written at the same single staging point.
// Everything else identical to R14.

typedef short short8 __attribute__((ext_vector_type(8)));
typedef float f32x4 __attribute__((ext_vector_type(4)));

__device__ __forceinline__ unsigned short bfbits(float f) {
  union { __hip_bfloat16 h; unsigned short u; } c;
  c.h = __float2bfloat16(f);   // hardware RNE
  return c.u;
}

__device__ __forceinline__ unsigned int bfpack(float a, float b) {
  return (unsigned int)bfbits(a) | ((unsigned int)bfbits(b) << 16);
}

__device__ __forceinline__ float fast_sigmoid(float z) {
  float e = __expf(-z);
  return __builtin_amdgcn_rcpf(1.0f + e);
}

__device__ __forceinline__ void lif4(f32x4& mv, const f32x4 av, float w2c, float pr[4]) {
#pragma unroll
  for (int e = 0; e < 4; ++e) {
    float m   = fmaf(mv[e], 0.9f, av[e]);     // beta*mem + cur1
    float spk = fast_sigmoid(fmaf(m, 10.f, -10.f));
    mv[e] = m - spk;
    pr[e] = fmaf(spk, w2c, pr[e]);
  }
}

__global__ void w1_to_bf16(const float* __restrict__ w1, unsigned short* __restrict__ o) {
  int i = blockIdx.x * 256 + threadIdx.x;      // 32768 float4s
  float4 v = reinterpret_cast<const float4*>(w1)[i];
  reinterpret_cast<uint2*>(o)[i] = make_uint2(bfpack(v.x, v.y), bfpack(v.z, v.w));
}

__device__ __forceinline__ short8 cvt_frag(const float* p) {
  const float4 v0 = *reinterpret_cast<const float4*>(p);
  const float4 v1 = *reinterpret_cast<const float4*>(p + 4);
  union { unsigned int u[4]; short8 s; } cv;
  cv.u[0] = bfpack(v0.x, v0.y);
  cv.u[1] = bfpack(v0.z, v0.w);
  cv.u[2] = bfpack(v1.x, v1.y);
  cv.u[3] = bfpack(v1.z, v1.w);
  return cv.s;
}

// 512 threads = 8 waves. Block: 32 batch rows; wave w owns 32 rows x h in [w*64, w*64+64).
template <bool USE_WS>
__global__
__attribute__((amdgpu_flat_work_group_size(512, 512)))
void snn_main(const float* __restrict__ x,
              const unsigned short* __restrict__ w1bf,  // bf16 W1 (if USE_WS)
              const float* __restrict__ w1f,            // fp32 W1 (fallback)
              const float* __restrict__ b1,
              const float* __restrict__ w2,
              const float* __restrict__ b2,
              float* __restrict__ out)
{
  // mem1 planes 0..4 in LDS (per-thread f32x4 slots, 0-conflict); planes 5,6,7 in regs
  __shared__ __align__(16) float mem_lds[5][512][4];       // 40,960 B
  __shared__ __align__(16) unsigned short xt[2][32][132];  // [half][row][col] 16,896 B
  __shared__ float red[32][9];                             // 1,152 B   (total 59,008 B)

  const int tid  = threadIdx.x;
  const int lane = tid & 63;
  const int wave = tid >> 6;          // 0..7
  const int l15  = lane & 15;
  const int lq   = lane >> 4;         // 0..3
  const long b0  = (long)blockIdx.x * 32;
  const int h0   = wave * 64;         // 4 col-tiles of 16

  float w2l[4], b1l[4];
#pragma unroll
  for (int ct = 0; ct < 4; ++ct) {
    int h = h0 + ct * 16 + l15;
    w2l[ct] = w2[h];
    b1l[ct] = b1[h];
  }
  const float bias2 = b2[0];

  // init mem1: LDS planes 0..4 (own slot; first barrier fences), reg planes 5..7
#pragma unroll
  for (int p = 0; p < 5; ++p) {
    f32x4 z = {0.f, 0.f, 0.f, 0.f};
    *reinterpret_cast<f32x4*>(&mem_lds[p][tid][0]) = z;
  }
  f32x4 m5 = {0.f, 0.f, 0.f, 0.f}, m6 = m5, m7 = m5;

  float mem2 = 0.f, spksum = 0.f;   // per-thread redundant (16 replicas per row)

  // staging: thread -> row sr (0..31), float4 col sc (0..15); 4 float4 per t (full row)
  const int sr = tid >> 4;
  const int sc = tid & 15;
  const float* xrow = x + (b0 + sr) * 2560;

  // W1 fragment base (ct offset = ct*4096 shorts / floats per use)
  const unsigned short* wb = w1bf + (h0 + l15) * 256 + lq * 8;
  const float*          wf = w1f  + (h0 + l15) * 256 + lq * 8;

  // prologue: load+pack full row of t=0 (pf = 4 uint2 = 8 VGPR)
  uint2 pf[4];
#pragma unroll
  for (int j = 0; j < 4; ++j) {
    const float4 v = *reinterpret_cast<const float4*>(xrow + sc * 4 + j * 64);
    pf[j] = make_uint2(bfpack(v.x, v.y), bfpack(v.z, v.w));
  }

#pragma unroll 1
  for (int t = 0; t < 10; ++t) {
    // ---- A: write pf(t) -> xt halves; issue+pack loads for t+1 (full-phase cover) ----
#pragma unroll
    for (int j = 0; j < 4; ++j)
      *reinterpret_cast<uint2*>(&xt[j >> 1][sr][sc * 4 + (j & 1) * 64]) = pf[j];
    {
      const int tn = (t < 9) ? t + 1 : 9;   // tail: harmless re-read
#pragma unroll
      for (int j = 0; j < 4; ++j) {
        const float4 v = *reinterpret_cast<const float4*>(xrow + tn * 256 + sc * 4 + j * 64);
        pf[j] = make_uint2(bfpack(v.x, v.y), bfpack(v.z, v.w));
      }
    }
    __syncthreads();   // bar1: xt ready

    // ======== PASS 0: col-tiles 0,1 ========
    f32x4 acc[2][2];
#pragma unroll
    for (int rt = 0; rt < 2; ++rt)
#pragma unroll
      for (int c = 0; c < 2; ++c) {
        f32x4 cc = { b1l[c], b1l[c], b1l[c], b1l[c] };
        acc[rt][c] = cc;
      }
#pragma unroll
    for (int kk = 0; kk < 8; ++kk) {
      short8 a[2], bfr[2];
#pragma unroll
      for (int rt = 0; rt < 2; ++rt)
        a[rt] = *reinterpret_cast<const short8*>(
            &xt[kk >> 2][rt * 16 + l15][(kk & 3) * 32 + lq * 8]);
#pragma unroll
      for (int c = 0; c < 2; ++c) {
        if constexpr (USE_WS) bfr[c] = *reinterpret_cast<const short8*>(wb + c * 4096 + kk * 32);
        else                  bfr[c] = cvt_frag(wf + c * 4096 + kk * 32);
      }
#pragma unroll
      for (int rt = 0; rt < 2; ++rt)
#pragma unroll
        for (int c = 0; c < 2; ++c)
          acc[rt][c] = __builtin_amdgcn_mfma_f32_16x16x32_bf16(a[rt], bfr[c], acc[rt][c], 0, 0, 0);
    }
    // LIF pass0: planes (rt0:c0,c1)->lds0,lds1 ; (rt1:c0)->lds4 ; (rt1:c1)->m5 ; red =
    {
      float pr[4] = {0.f, 0.f, 0.f, 0.f};
      f32x4 mv;
      mv = *reinterpret_cast<f32x4*>(&mem_lds[0][tid][0]);
      lif4(mv, acc[0][0], w2l[0], pr);
      *reinterpret_cast<f32x4*>(&mem_lds[0][tid][0]) = mv;
      mv = *reinterpret_cast<f32x4*>(&mem_lds[1][tid][0]);
      lif4(mv, acc[0][1], w2l[1], pr);
      *reinterpret_cast<f32x4*>(&mem_lds[1][tid][0]) = mv;
#pragma unroll
      for (int e = 0; e < 4; ++e) {
        float v = pr[e];
        v += __shfl_xor(v, 1); v += __shfl_xor(v, 2);
        v += __shfl_xor(v, 4); v += __shfl_xor(v, 8);
        if (l15 == 0) red[lq * 4 + e][wave] = v;
      }
      float pr1[4] = {0.f, 0.f, 0.f, 0.f};
      mv = *reinterpret_cast<f32x4*>(&mem_lds[4][tid][0]);
      lif4(mv, acc[1][0], w2l[0], pr1);
      *reinterpret_cast<f32x4*>(&mem_lds[4][tid][0]) = mv;
      lif4(m5, acc[1][1], w2l[1], pr1);
#pragma unroll
      for (int e = 0; e < 4; ++e) {
        float v = pr1[e];
        v += __shfl_xor(v, 1); v += __shfl_xor(v, 2);
        v += __shfl_xor(v, 4); v += __shfl_xor(v, 8);
        if (l15 == 0) red[16 + lq * 4 + e][wave] = v;
      }
    }

    // ======== PASS 1: col-tiles 2,3 ========
#pragma unroll
    for (int rt = 0; rt < 2; ++rt)
#pragma unroll
      for (int c = 0; c < 2; ++c) {
        f32x4 cc = { b1l[2 + c], b1l[2 + c], b1l[2 + c], b1l[2 + c] };
        acc[rt][c] = cc;
      }
#pragma unroll
    for (int kk = 0; kk < 8; ++kk) {
      short8 a[2], bfr[2];
#pragma unroll
      for (int rt = 0; rt < 2; ++rt)
        a[rt] = *reinterpret_cast<const short8*>(
            &xt[kk >> 2][rt * 16 + l15][(kk & 3) * 32 + lq * 8]);
#pragma unroll
      for (int c = 0; c < 2; ++c) {
        if constexpr (USE_WS) bfr[c] = *reinterpret_cast<const short8*>(wb + (2 + c) * 4096 + kk * 32);
        else                  bfr[c] = cvt_frag(wf + (2 + c) * 4096 + kk * 32);
      }
#pragma unroll
      for (int rt = 0; rt < 2; ++rt)
#pragma unroll
        for (int c = 0; c < 2; ++c)
          acc[rt][c] = __builtin_amdgcn_mfma_f32_16x16x32_bf16(a[rt], bfr[c], acc[rt][c], 0, 0, 0);
    }
    // LIF pass1: (rt0:c2)->lds2 ; (rt0:c3)->lds3 ; (rt1:c2)->m6 ; (rt1:c3)->m7 ; red +=
    {
      float pr[4] = {0.f, 0.f, 0.f, 0.f};
      f32x4 mv;
      mv = *reinterpret_cast<f32x4*>(&mem_lds[2][tid][0]);
      lif4(mv, acc[0][0], w2l[2], pr);
      *reinterpret_cast<f32x4*>(&mem_lds[2][tid][0]) = mv;
      mv = *reinterpret_cast<f32x4*>(&mem_lds[3][tid][0]);
      lif4(mv, acc[0][1], w2l[3], pr);
      *reinterpret_cast<f32x4*>(&mem_lds[3][tid][0]) = mv;
#pragma unroll
      for (int e = 0; e < 4; ++e) {
        float v = pr[e];
        v += __shfl_xor(v, 1); v += __shfl_xor(v, 2);
        v += __shfl_xor(v, 4); v += __shfl_xor(v, 8);
        if (l15 == 0) red[lq * 4 + e][wave] += v;
      }
      float pr1[4] = {0.f, 0.f, 0.f, 0.f};
      lif4(m6, acc[1][0], w2l[2], pr1);
      lif4(m7, acc[1][1], w2l[3], pr1);
#pragma unroll
      for (int e = 0; e < 4; ++e) {
        float v = pr1[e];
        v += __shfl_xor(v, 1); v += __shfl_xor(v, 2);
        v += __shfl_xor(v, 4); v += __shfl_xor(v, 8);
        if (l15 == 0) red[16 + lq * 4 + e][wave] += v;
      }
    }
    __syncthreads();   // bar2: red complete; xt reads done (A(t+1) may overwrite)

    // ---- LIF2, redundant on all threads (row = lane&31) ----
    {
      float c2 = bias2;
#pragma unroll
      for (int w = 0; w < 8; ++w) c2 += red[lane & 31][w];
      float m   = fmaf(mem2, 0.9f, c2);
      float spk = fast_sigmoid(fmaf(m, 10.f, -10.f));
      mem2   = m - spk;
      spksum += spk;
    }
  }

  if (tid < 32) {
    float y = fast_sigmoid(spksum * 0.1f);
    out[b0 + tid] = y;                      // FLOAT32 output
  }
}

extern "C" void kernel_launch(void* const* d_in, const int* in_sizes, int n_in,
                              void* d_out, int out_size, void* d_ws, size_t ws_size,
                              hipStream_t stream) {
  const float* x  = (const float*)d_in[0];
  const float* W1 = (const float*)d_in[1];
  const float* b1 = (const float*)d_in[2];
  const float* W2 = (const float*)d_in[3];
  const float* b2 = (const float*)d_in[4];
  float* out = (float*)d_out;
  (void)in_sizes; (void)n_in;

  const int grid = out_size / 32;   // out_size == B == 32768 -> 1024 blocks

  if (ws_size >= 512 * 256 * sizeof(unsigned short)) {
    unsigned short* w1bf = (unsigned short*)d_ws;   // 256 KB
    w1_to_bf16<<<128, 256, 0, stream>>>(W1, w1bf);
    snn_main<true><<<grid, 512, 0, stream>>>(x, w1bf, W1, b1, W2, b2, out);
  } else {
    snn_main<false><<<grid, 512, 0, stream>>>(x, nullptr, W1, b1, W2, b2, out);
  }
}